// Round 13
// baseline (61.927 us; speedup 1.0000x reference)
//
#include <hip/hip_runtime.h>

// Problem constants: B=8, H=320, W=1024, CH=CW=3, MAXINS=200
#define BATCH   8
#define HW      (320 * 1024)        // 327680 pixels per batch (mult of 4)
#define ELEMS   (HW * 9)            // 2949120 floats per batch
#define MAXINS  200
#define BINS    (MAXINS * 9)        // 1800 bins; stride 9: gcd(9,32)=1 -> full
                                    // 32-bank spread (stride 12 was 8-way)
#define NXBLK   320                 // compress x-blocks per batch
#define QPB     256                 // pixel-quads per block = 1 per thread
#define SCALE      2097152.0f       // 2^21 fixed-point scale
#define INV_SCALE_D (1.1 / 2097152.0)

// Decode an 8-element group starting at e (inflate path): spans <=2 pixels.
__device__ __forceinline__ void decode8(int e, int& pix0, int& pix1,
                                        int& j0, int& b) {
    pix0 = e / 9;
    j0   = e - pix0 * 9;
    b    = 9 - j0;
    pix1 = (e + 7) / 9;
}

// ---------------------------------------------------------------------------
// Compress, quad-pixel, 1 quad/thread, 2560 blocks (10/CU): latency hiding
// via TLP (R11 counters: 39% occupancy, 9% VALU, 32% BW -> latency-bound).
// All (pixel, j) decomposition compile-time; LDS stride 9; int fixed-point
// histogram (native ds_add); native global int-atomic flush.
// ---------------------------------------------------------------------------
__global__ __launch_bounds__(256) void epp_compress(
    const int* __restrict__ inst, const float* __restrict__ src,
    int* __restrict__ compi)
{
    __shared__ int bins[BINS];
    const int b = blockIdx.y;

    for (int i = threadIdx.x; i < BINS; i += 256) bins[i] = 0;
    __syncthreads();

    const int* __restrict__ instb = inst + b * HW;
    const float4* __restrict__ srcb = (const float4*)(src + (size_t)b * ELEMS);

    const int q = blockIdx.x * QPB + threadIdx.x;    // pixel-quad index
    const int p = q * 4;                             // first pixel (4-aligned)
    const int4 ids = *(const int4*)(instb + p);      // 16B-aligned id load
    int base[4] = {ids.x * 9, ids.y * 9, ids.z * 9, ids.w * 9};

    const float4* s = srcb + (size_t)q * 9;          // 36 floats, 16B-aligned
    float4 f[9];
#pragma unroll
    for (int r = 0; r < 9; ++r) f[r] = s[r];

#pragma unroll
    for (int r = 0; r < 9; ++r) {
        const float v[4] = {f[r].x, f[r].y, f[r].z, f[r].w};
#pragma unroll
        for (int c = 0; c < 4; ++c) {
            const int i  = 4 * r + c;                // 0..35, static
            const int px = i / 9;                    // static
            const int j  = i - px * 9;               // static
            atomicAdd(&bins[base[px] + j],           // ds_add, imm offset j
                      __float2int_rn(v[c] * SCALE));
        }
    }
    __syncthreads();

    // Identity flush: native global int atomics into the per-batch table.
    int* __restrict__ cb = compi + b * BINS;
    for (int i = threadIdx.x; i < BINS; i += 256) {
        atomicAdd(&cb[i], bins[i]);
    }
}

// ---------------------------------------------------------------------------
// Inflate (measured ~85% of write ceiling in R11 diagnostic — leave alone):
// stage table in LDS converting int->float with 1.1/SCALE folded; decode8
// gather; coalesced float4 stores.
// ---------------------------------------------------------------------------
__global__ __launch_bounds__(256) void epp_inflate(
    const int* __restrict__ inst, const int* __restrict__ compi,
    float* __restrict__ out)
{
    __shared__ float bins[BINS];
    const int b = blockIdx.y;
    const int* __restrict__ cb = compi + b * BINS;
    for (int i = threadIdx.x; i < BINS; i += 256) {
        bins[i] = (float)((double)cb[i] * INV_SCALE_D);
    }
    __syncthreads();

    const int total8 = ELEMS / 8;
    const int* __restrict__ instb = inst + b * HW;
    float4* __restrict__ outb = (float4*)(out + (size_t)b * ELEMS);
    const int stride = gridDim.x * 256;

    for (int g = blockIdx.x * 256 + threadIdx.x; g < total8; g += stride) {
        const int e = g * 8;
        int pix0, pix1, j0, cnt8;
        decode8(e, pix0, pix1, j0, cnt8);
        const int id0 = instb[pix0] * 9 + j0;
        const int id1 = instb[pix1] * 9 + j0 - 9;
        float vals[8];
#pragma unroll
        for (int k = 0; k < 8; ++k) {
            int base = (k < cnt8) ? id0 : id1;
            vals[k] = bins[base + k];
        }
        outb[2 * g]     = make_float4(vals[0], vals[1], vals[2], vals[3]);
        outb[2 * g + 1] = make_float4(vals[4], vals[5], vals[6], vals[7]);
    }
}

extern "C" void kernel_launch(void* const* d_in, const int* in_sizes, int n_in,
                              void* d_out, int out_size, void* d_ws, size_t ws_size,
                              hipStream_t stream) {
    const int*   inst = (const int*)d_in[0];    // [B,1,H,W] int32
    const float* src  = (const float*)d_in[1];  // [B,H,W,3,3] f32
    float* out = (float*)d_out;                 // [B,H,W,3,3] f32

    const size_t compBytes = (size_t)BATCH * BINS * sizeof(int);   // 57.6 KB
    if (ws_size < compBytes) return;            // ws has always been >= 300MB

    int* compi = (int*)d_ws;

    // Zero the int accumulator every call (graph-safe, 57.6 KB).
    (void)hipMemsetAsync(compi, 0, compBytes, stream);

    dim3 cgrid(NXBLK, BATCH);                   // 2560 blocks, 1 quad/thread
    epp_compress<<<cgrid, 256, 0, stream>>>(inst, src, compi);

    dim3 igrid(512, BATCH);                     // 4096 blocks (proven config)
    epp_inflate<<<igrid, 256, 0, stream>>>(inst, compi, out);
}

// Round 14
// 50.535 us; speedup vs baseline: 1.2254x; 1.2254x over previous
//
#include <hip/hip_runtime.h>

// Problem constants: B=8, H=320, W=1024, CH=CW=3, MAXINS=200
#define BATCH   8
#define HW      (320 * 1024)        // 327680 pixels per batch (mult of 4)
#define ELEMS   (HW * 9)            // 2949120 floats per batch
#define MAXINS  200
#define BINS    (MAXINS * 9)        // 1800 bins; stride 9: gcd(9,32)=1 -> full
                                    // 32-bank spread
#define NXBLK   160                 // compress x-blocks per batch
#define CBLK    512                 // compress block size: 8 waves/block,
                                    // 4 blocks/CU resident = 32 waves = cap,
                                    // 1280 blocks = 5/CU exactly even,
                                    // histogram count unchanged vs R12
#define SCALE      2097152.0f       // 2^21 fixed-point scale
#define INV_SCALE_D (1.1 / 2097152.0)

// Decode an 8-element group starting at e (inflate path): spans <=2 pixels.
__device__ __forceinline__ void decode8(int e, int& pix0, int& pix1,
                                        int& j0, int& b) {
    pix0 = e / 9;
    j0   = e - pix0 * 9;
    b    = 9 - j0;
    pix1 = (e + 7) / 9;
}

// ---------------------------------------------------------------------------
// Compress, quad-pixel, 512-thread blocks, 1 quad/thread.
// R13 lesson: extra blocks double flush fixed cost (+11us) — raise waves/CU
// with bigger blocks instead (same 1280 histograms, 20 -> 32 waves/CU).
// ---------------------------------------------------------------------------
__global__ __launch_bounds__(CBLK) void epp_compress(
    const int* __restrict__ inst, const float* __restrict__ src,
    int* __restrict__ compi)
{
    __shared__ int bins[BINS];
    const int b = blockIdx.y;

    for (int i = threadIdx.x; i < BINS; i += CBLK) bins[i] = 0;
    __syncthreads();

    const int* __restrict__ instb = inst + b * HW;
    const float4* __restrict__ srcb = (const float4*)(src + (size_t)b * ELEMS);

    const int q = blockIdx.x * CBLK + threadIdx.x;   // pixel-quad index
    const int p = q * 4;                             // first pixel (4-aligned)
    const int4 ids = *(const int4*)(instb + p);      // 16B-aligned id load
    int base[4] = {ids.x * 9, ids.y * 9, ids.z * 9, ids.w * 9};

    const float4* s = srcb + (size_t)q * 9;          // 36 floats, 16B-aligned
    float4 f[9];
#pragma unroll
    for (int r = 0; r < 9; ++r) f[r] = s[r];

#pragma unroll
    for (int r = 0; r < 9; ++r) {
        const float v[4] = {f[r].x, f[r].y, f[r].z, f[r].w};
#pragma unroll
        for (int c = 0; c < 4; ++c) {
            const int i  = 4 * r + c;                // 0..35, static
            const int px = i / 9;                    // static
            const int j  = i - px * 9;               // static
            atomicAdd(&bins[base[px] + j],           // ds_add, imm offset j
                      __float2int_rn(v[c] * SCALE));
        }
    }
    __syncthreads();

    // Identity flush: native global int atomics into the per-batch table.
    int* __restrict__ cb = compi + b * BINS;
    for (int i = threadIdx.x; i < BINS; i += CBLK) {
        atomicAdd(&cb[i], bins[i]);
    }
}

// ---------------------------------------------------------------------------
// Inflate (measured at its R+W roofline in R11: 16.5us — unchanged):
// stage table in LDS converting int->float with 1.1/SCALE folded; decode8
// gather; coalesced float4 stores.
// ---------------------------------------------------------------------------
__global__ __launch_bounds__(256) void epp_inflate(
    const int* __restrict__ inst, const int* __restrict__ compi,
    float* __restrict__ out)
{
    __shared__ float bins[BINS];
    const int b = blockIdx.y;
    const int* __restrict__ cb = compi + b * BINS;
    for (int i = threadIdx.x; i < BINS; i += 256) {
        bins[i] = (float)((double)cb[i] * INV_SCALE_D);
    }
    __syncthreads();

    const int total8 = ELEMS / 8;
    const int* __restrict__ instb = inst + b * HW;
    float4* __restrict__ outb = (float4*)(out + (size_t)b * ELEMS);
    const int stride = gridDim.x * 256;

    for (int g = blockIdx.x * 256 + threadIdx.x; g < total8; g += stride) {
        const int e = g * 8;
        int pix0, pix1, j0, cnt8;
        decode8(e, pix0, pix1, j0, cnt8);
        const int id0 = instb[pix0] * 9 + j0;
        const int id1 = instb[pix1] * 9 + j0 - 9;
        float vals[8];
#pragma unroll
        for (int k = 0; k < 8; ++k) {
            int base = (k < cnt8) ? id0 : id1;
            vals[k] = bins[base + k];
        }
        outb[2 * g]     = make_float4(vals[0], vals[1], vals[2], vals[3]);
        outb[2 * g + 1] = make_float4(vals[4], vals[5], vals[6], vals[7]);
    }
}

extern "C" void kernel_launch(void* const* d_in, const int* in_sizes, int n_in,
                              void* d_out, int out_size, void* d_ws, size_t ws_size,
                              hipStream_t stream) {
    const int*   inst = (const int*)d_in[0];    // [B,1,H,W] int32
    const float* src  = (const float*)d_in[1];  // [B,H,W,3,3] f32
    float* out = (float*)d_out;                 // [B,H,W,3,3] f32

    const size_t compBytes = (size_t)BATCH * BINS * sizeof(int);   // 57.6 KB
    if (ws_size < compBytes) return;            // ws has always been >= 300MB

    int* compi = (int*)d_ws;

    // Zero the int accumulator every call (graph-safe, 57.6 KB).
    (void)hipMemsetAsync(compi, 0, compBytes, stream);

    dim3 cgrid(NXBLK, BATCH);                   // 1280 blocks x 512 threads
    epp_compress<<<cgrid, CBLK, 0, stream>>>(inst, src, compi);

    dim3 igrid(512, BATCH);                     // 4096 blocks (proven config)
    epp_inflate<<<igrid, 256, 0, stream>>>(inst, compi, out);
}